// Round 5
// baseline (247.619 us; speedup 1.0000x reference)
//
#include <hip/hip_runtime.h>
#include <math.h>

// LayerSumSimple: K-level chained cummax-of-sums == max-plus affine scan with
// 8-element state s:  s[k] <- max(s[k], s[k-1] + g_k(t)),  g_k = x*w[k]+b[k].
// 5 launches, all 64-thread single-wave blocks:
//   pass1 : per-chunk max-plus affine summary, transposed float4 layout
//   pass2a: compose G=8 chunk maps -> group maps (512 blocks, ring-2 f4 prefetch)
//   pass2b: serial scan over NG=16 group maps -> group inflows (32 blocks)
//   pass2c: replay chunk maps within groups -> chunk inflows (512 blocks)
//   pass3 : re-scan each chunk from true inflow, emit outputs
namespace {
constexpr int BB   = 8;
constexpr int TT   = 8192;
constexpr int DD   = 256;
constexpr int KK   = 8;
constexpr int TOUT = TT - KK + 1;       // 8185
constexpr int NSUM = 36;                // 8 c-vec + 28 strict-lower A = 9 float4
constexpr int C    = 128;               // chunks per sequence
constexpr int L    = TT / C;            // 64
constexpr int G    = 8;                 // chunks per group
constexpr int NG   = C / G;             // 16
constexpr int MSZ  = NSUM * 64;         // floats per map region (chunk, dg): 2304
constexpr int ISZ  = KK * 64;           // floats per inflow region: 512

__host__ __device__ __forceinline__ constexpr int tri(int k, int j) {
    return 8 + k * (k - 1) / 2 + j;     // k in [1,8), j < k  (max 35)
}

// one time-step of the summary recurrence (descending k uses OLD row k-1)
__device__ __forceinline__ void step_sum(float x, const float (&wk)[KK],
                                         const float (&bk)[KK],
                                         float (&A)[KK][KK], float (&cv)[KK])
{
    float g[KK];
    #pragma unroll
    for (int k = 0; k < KK; ++k) g[k] = fmaf(x, wk[k], bk[k]);
    #pragma unroll
    for (int k = KK - 1; k >= 1; --k) {
        #pragma unroll
        for (int j = 0; j < k - 1; ++j)
            A[k][j] = fmaxf(A[k][j], g[k] + A[k - 1][j]);
        A[k][k - 1] = fmaxf(A[k][k - 1], g[k]);  // A[k-1][k-1] == 0 (diag)
        cv[k] = fmaxf(cv[k], g[k] + cv[k - 1]);
    }
    cv[0] = fmaxf(cv[0], g[0]);
}

// ---- pass 1: block = (b, c, dg); 64 thr; 8-deep ping-pong pipeline ----
constexpr int U1 = 8;
__global__ __launch_bounds__(64) void pass1_summaries(
    const float* __restrict__ X, const float* __restrict__ W,
    const float* __restrict__ Bv, float* __restrict__ sum)
{
    const int bid = blockIdx.x;             // ((b*C + c)*4 + dg) == map region id
    const int dg  = bid & 3;
    const int c   = (bid >> 2) & (C - 1);
    const int b   = bid >> 9;               // C*4 = 512
    const int l   = threadIdx.x;
    const int d   = dg * 64 + l;

    float wk[KK], bk[KK];
    #pragma unroll
    for (int k = 0; k < KK; ++k) { wk[k] = W[k * DD + d]; bk[k] = Bv[k * DD + d]; }

    float cv[KK];
    float A[KK][KK];
    #pragma unroll
    for (int k = 0; k < KK; ++k) {
        cv[k] = -INFINITY;
        #pragma unroll
        for (int j = 0; j < KK; ++j) A[k][j] = -INFINITY;
    }

    const float* xp = X + (b * TT + c * L) * DD + d;
    constexpr int nb = L / U1;              // 8
    float x0[U1], x1[U1];
    #pragma unroll
    for (int u = 0; u < U1; ++u) x0[u] = xp[u * DD];

    #pragma unroll
    for (int ib = 0; ib < nb; ib += 2) {
        const float* p1 = xp + (ib + 1) * U1 * DD;
        #pragma unroll
        for (int u = 0; u < U1; ++u) x1[u] = p1[u * DD];
        #pragma unroll
        for (int u = 0; u < U1; ++u) step_sum(x0[u], wk, bk, A, cv);
        if (ib + 2 < nb) {
            const float* p2 = xp + (ib + 2) * U1 * DD;
            #pragma unroll
            for (int u = 0; u < U1; ++u) x0[u] = p2[u * DD];
        }
        #pragma unroll
        for (int u = 0; u < U1; ++u) step_sum(x1[u], wk, bk, A, cv);
    }

    // transposed store: thread's 36 entries contiguous -> 9 float4 stores
    alignas(16) float o[NSUM];
    #pragma unroll
    for (int k = 0; k < KK; ++k) o[k] = cv[k];
    #pragma unroll
    for (int k = 1; k < KK; ++k) {
        #pragma unroll
        for (int j = 0; j < k; ++j) o[tri(k, j)] = A[k][j];
    }
    float4* sp = (float4*)(sum + bid * MSZ + l * NSUM);
    const float4* o4 = (const float4*)o;
    #pragma unroll
    for (int i = 0; i < 9; ++i) sp[i] = o4[i];
}

// load one map (9 float4) for region r, thread l
__device__ __forceinline__ void ld_map(const float* __restrict__ base, int r,
                                       int l, float (&m)[NSUM])
{
    const float4* sp = (const float4*)(base + r * MSZ + l * NSUM);
    float4* m4 = (float4*)m;
    #pragma unroll
    for (int i = 0; i < 9; ++i) m4[i] = sp[i];
}

// ---- pass 2a: block = (b, g, dg); compose G chunk maps, ring-2 prefetch ----
__global__ __launch_bounds__(64) void pass2a_groups(
    const float* __restrict__ sum, float* __restrict__ gsum)
{
    const int bid = blockIdx.x;             // ((b*NG + g)*4 + dg)
    const int dg  = bid & 3;
    const int g   = (bid >> 2) & (NG - 1);
    const int b   = bid >> 6;               // NG*4 = 64
    const int l   = threadIdx.x;

    float R[KK][KK], cv[KK];
    #pragma unroll
    for (int i = 0; i < KK; ++i) {
        cv[i] = -INFINITY;
        #pragma unroll
        for (int j = 0; j < KK; ++j) R[i][j] = -INFINITY;
    }

    alignas(16) float m0[NSUM], m1[NSUM];
    auto COMPOSE = [&](const float (&m)[NSUM]) {
        float nc[KK];
        #pragma unroll
        for (int i = 0; i < KK; ++i) {
            float v = fmaxf(m[i], cv[i]);
            #pragma unroll
            for (int j = 0; j < i; ++j) v = fmaxf(v, m[tri(i, j)] + cv[j]);
            nc[i] = v;
        }
        float nR[KK][KK];
        #pragma unroll
        for (int i = 1; i < KK; ++i) {
            #pragma unroll
            for (int j = 0; j < i; ++j) {
                float v = fmaxf(R[i][j], m[tri(i, j)]);
                #pragma unroll
                for (int mm = j + 1; mm < i; ++mm)
                    v = fmaxf(v, m[tri(i, mm)] + R[mm][j]);
                nR[i][j] = v;
            }
        }
        #pragma unroll
        for (int i = 0; i < KK; ++i) {
            cv[i] = nc[i];
            #pragma unroll
            for (int j = 0; j < i; ++j) R[i][j] = nR[i][j];
        }
    };
    auto REG = [&](int c) { return ((b * C + c) * 4 + dg); };

    const int c0 = g * G;
    ld_map(sum, REG(c0), l, m0);
    #pragma unroll
    for (int ci = 0; ci < G; ci += 2) {
        ld_map(sum, REG(c0 + ci + 1), l, m1);
        COMPOSE(m0);
        if (ci + 2 < G) ld_map(sum, REG(c0 + ci + 2), l, m0);
        COMPOSE(m1);
    }

    alignas(16) float o[NSUM];
    #pragma unroll
    for (int i = 0; i < KK; ++i) o[i] = cv[i];
    #pragma unroll
    for (int i = 1; i < KK; ++i) {
        #pragma unroll
        for (int j = 0; j < i; ++j) o[tri(i, j)] = R[i][j];
    }
    float4* gp = (float4*)(gsum + bid * MSZ + l * NSUM);
    const float4* o4 = (const float4*)o;
    #pragma unroll
    for (int i = 0; i < 9; ++i) gp[i] = o4[i];
}

// ---- pass 2b: block = (b, dg); serial scan over NG group maps ----
__global__ __launch_bounds__(64) void pass2b_scan_groups(
    const float* __restrict__ gsum, float* __restrict__ ginfl)
{
    const int bid = blockIdx.x;             // b*4 + dg
    const int dg  = bid & 3;
    const int b   = bid >> 2;
    const int l   = threadIdx.x;

    alignas(16) float s[KK];
    #pragma unroll
    for (int k = 0; k < KK; ++k) s[k] = -INFINITY;

    alignas(16) float m0[NSUM], m1[NSUM];
    auto APPLY = [&](const float (&m)[NSUM]) {
        float ns[KK];
        #pragma unroll
        for (int k = 0; k < KK; ++k) ns[k] = fmaxf(m[k], s[k]);
        #pragma unroll
        for (int k = 1; k < KK; ++k) {
            #pragma unroll
            for (int j = 0; j < k; ++j) ns[k] = fmaxf(ns[k], m[tri(k, j)] + s[j]);
        }
        #pragma unroll
        for (int k = 0; k < KK; ++k) s[k] = ns[k];
    };
    auto REG = [&](int g) { return ((b * NG + g) * 4 + dg); };
    auto ST  = [&](int g) {
        float4* ip = (float4*)(ginfl + REG(g) * ISZ + l * KK);
        ip[0] = ((const float4*)s)[0];
        ip[1] = ((const float4*)s)[1];
    };

    ld_map(gsum, REG(0), l, m0);
    #pragma unroll
    for (int g = 0; g < NG; g += 2) {
        ld_map(gsum, REG(g + 1), l, m1);
        ST(g);     APPLY(m0);
        if (g + 2 < NG) ld_map(gsum, REG(g + 2), l, m0);
        ST(g + 1); APPLY(m1);
    }
}

// ---- pass 2c: block = (b, g, dg); replay chunk maps -> chunk inflows ----
__global__ __launch_bounds__(64) void pass2c_chunk_inflows(
    const float* __restrict__ sum, const float* __restrict__ ginfl,
    float* __restrict__ infl)
{
    const int bid = blockIdx.x;             // ((b*NG + g)*4 + dg)
    const int dg  = bid & 3;
    const int g   = (bid >> 2) & (NG - 1);
    const int b   = bid >> 6;
    const int l   = threadIdx.x;

    alignas(16) float s[KK];
    {
        const float4* gp = (const float4*)(ginfl + bid * ISZ + l * KK);
        ((float4*)s)[0] = gp[0];
        ((float4*)s)[1] = gp[1];
    }

    alignas(16) float m0[NSUM], m1[NSUM];
    auto APPLY = [&](const float (&m)[NSUM]) {
        float ns[KK];
        #pragma unroll
        for (int k = 0; k < KK; ++k) ns[k] = fmaxf(m[k], s[k]);
        #pragma unroll
        for (int k = 1; k < KK; ++k) {
            #pragma unroll
            for (int j = 0; j < k; ++j) ns[k] = fmaxf(ns[k], m[tri(k, j)] + s[j]);
        }
        #pragma unroll
        for (int k = 0; k < KK; ++k) s[k] = ns[k];
    };
    auto REG = [&](int c) { return ((b * C + c) * 4 + dg); };
    auto ST  = [&](int c) {
        float4* ip = (float4*)(infl + REG(c) * ISZ + l * KK);
        ip[0] = ((const float4*)s)[0];
        ip[1] = ((const float4*)s)[1];
    };

    const int c0 = g * G;
    ld_map(sum, REG(c0), l, m0);
    #pragma unroll
    for (int ci = 0; ci < G; ci += 2) {
        ld_map(sum, REG(c0 + ci + 1), l, m1);
        ST(c0 + ci);     APPLY(m0);
        if (ci + 2 < G) ld_map(sum, REG(c0 + ci + 2), l, m0);
        ST(c0 + ci + 1); APPLY(m1);
    }
}

// ---- pass 3: block = (b, c, dg); 64 thr; scan from inflow, emit outputs ----
constexpr int U3 = 8;
__global__ __launch_bounds__(64) void pass3_scan(
    const float* __restrict__ X, const float* __restrict__ W,
    const float* __restrict__ Bv, const float* __restrict__ infl,
    float* __restrict__ out)
{
    const int bid = blockIdx.x;             // ((b*C + c)*4 + dg)
    const int dg  = bid & 3;
    const int c   = (bid >> 2) & (C - 1);
    const int b   = bid >> 9;
    const int l   = threadIdx.x;
    const int d   = dg * 64 + l;

    float wk[KK], bk[KK];
    #pragma unroll
    for (int k = 0; k < KK; ++k) { wk[k] = W[k * DD + d]; bk[k] = Bv[k * DD + d]; }

    alignas(16) float s[KK];
    {
        const float4* ip = (const float4*)(infl + bid * ISZ + l * KK);
        ((float4*)s)[0] = ip[0];
        ((float4*)s)[1] = ip[1];
    }

    const int t0 = c * L;
    const float* xp = X + (b * TT + t0) * DD + d;
    float* op = out + b * TOUT * DD + d;

    constexpr int nb = L / U3;              // 8
    float x0[U3], x1[U3];
    #pragma unroll
    for (int u = 0; u < U3; ++u) x0[u] = xp[u * DD];

    int t = t0;
    #pragma unroll
    for (int ib = 0; ib < nb; ib += 2) {
        const float* p1 = xp + (ib + 1) * U3 * DD;
        #pragma unroll
        for (int u = 0; u < U3; ++u) x1[u] = p1[u * DD];
        #pragma unroll
        for (int u = 0; u < U3; ++u) {
            float g[KK];
            #pragma unroll
            for (int k = 0; k < KK; ++k) g[k] = fmaf(x0[u], wk[k], bk[k]);
            #pragma unroll
            for (int k = KK - 1; k >= 1; --k) s[k] = fmaxf(s[k], s[k - 1] + g[k]);
            s[0] = fmaxf(s[0], g[0]);
            if (t >= KK - 1) op[(t - (KK - 1)) * DD] = s[KK - 1];
            ++t;
        }
        if (ib + 2 < nb) {
            const float* p2 = xp + (ib + 2) * U3 * DD;
            #pragma unroll
            for (int u = 0; u < U3; ++u) x0[u] = p2[u * DD];
        }
        #pragma unroll
        for (int u = 0; u < U3; ++u) {
            float g[KK];
            #pragma unroll
            for (int k = 0; k < KK; ++k) g[k] = fmaf(x1[u], wk[k], bk[k]);
            #pragma unroll
            for (int k = KK - 1; k >= 1; --k) s[k] = fmaxf(s[k], s[k - 1] + g[k]);
            s[0] = fmaxf(s[0], g[0]);
            if (t >= KK - 1) op[(t - (KK - 1)) * DD] = s[KK - 1];
            ++t;
        }
    }
}
} // namespace

extern "C" void kernel_launch(void* const* d_in, const int* in_sizes, int n_in,
                              void* d_out, int out_size, void* d_ws, size_t ws_size,
                              hipStream_t stream)
{
    const float* X  = (const float*)d_in[0];
    const float* W  = (const float*)d_in[1];
    const float* Bv = (const float*)d_in[2];
    float* out = (float*)d_out;

    // ws: sum 37.7 MB + gsum 4.7 MB + ginfl 1.05 MB + infl 8.4 MB = 51.9 MB
    float* sum   = (float*)d_ws;
    float* gsum  = sum   + (size_t)BB * C  * 4 * MSZ;
    float* ginfl = gsum  + (size_t)BB * NG * 4 * MSZ;
    float* infl  = ginfl + (size_t)BB * NG * 4 * ISZ;

    pass1_summaries<<<BB * C * 4, 64, 0, stream>>>(X, W, Bv, sum);
    pass2a_groups<<<BB * NG * 4, 64, 0, stream>>>(sum, gsum);
    pass2b_scan_groups<<<BB * 4, 64, 0, stream>>>(gsum, ginfl);
    pass2c_chunk_inflows<<<BB * NG * 4, 64, 0, stream>>>(sum, ginfl, infl);
    pass3_scan<<<BB * C * 4, 64, 0, stream>>>(X, W, Bv, infl, out);
}

// Round 7
// 166.102 us; speedup vs baseline: 1.4908x; 1.4908x over previous
//
#include <hip/hip_runtime.h>
#include <math.h>

// LayerSumSimple: K-level chained cummax-of-sums == max-plus affine scan with
// 8-element state s:  s[k] <- max(s[k], s[k-1] + g_k(t)),  g_k = x*w[k]+b[k].
// All workspace arrays use PLANE layout: plane i of region r at
// base[r*NPLANES*DD + i*DD + d] -> lane d accesses are fully coalesced.
// 5 launches:
//   pass1 : per-chunk max-plus affine summary (depth L=64 per block)
//   pass2a: compose G=8 chunk maps -> group maps      (128 blocks, depth 8)
//   pass2b: serial scan over NG=16 group maps         (8 blocks,  depth 16)
//   pass2c: replay chunk maps -> chunk inflow states  (128 blocks, depth 8)
//   pass3 : re-scan each chunk from true inflow, emit outputs
//           (FIXED round-6 bug: op stayed advancing while t was cumulative)
namespace {
constexpr int BB   = 8;
constexpr int TT   = 8192;
constexpr int DD   = 256;
constexpr int KK   = 8;
constexpr int TOUT = TT - KK + 1;       // 8185
constexpr int NSUM = 36;                // 8 c-vec + 28 strict-lower A
constexpr int C    = 128;               // chunks per sequence
constexpr int L    = TT / C;            // 64
constexpr int G    = 8;                 // chunks per group
constexpr int NG   = C / G;             // 16
constexpr int U    = 8;                 // pipeline batch (steps)
constexpr int NB   = L / U;             // 8 batches per chunk

__host__ __device__ __forceinline__ constexpr int tri(int k, int j) {
    return 8 + k * (k - 1) / 2 + j;     // k in [1,8), j < k  (max 35)
}

// one time-step of the summary recurrence (descending k uses OLD row k-1)
__device__ __forceinline__ void step_sum(float x, const float (&wk)[KK],
                                         const float (&bk)[KK],
                                         float (&A)[KK][KK], float (&cv)[KK])
{
    float g[KK];
    #pragma unroll
    for (int k = 0; k < KK; ++k) g[k] = fmaf(x, wk[k], bk[k]);
    #pragma unroll
    for (int k = KK - 1; k >= 1; --k) {
        #pragma unroll
        for (int j = 0; j < k - 1; ++j)
            A[k][j] = fmaxf(A[k][j], g[k] + A[k - 1][j]);
        A[k][k - 1] = fmaxf(A[k][k - 1], g[k]);  // A[k-1][k-1] == 0 (diag)
        cv[k] = fmaxf(cv[k], g[k] + cv[k - 1]);
    }
    cv[0] = fmaxf(cv[0], g[0]);
}

// ---- pass 1: one block per (b, chunk); thread d = channel ----
__global__ __launch_bounds__(256) void pass1_summaries(
    const float* __restrict__ X, const float* __restrict__ W,
    const float* __restrict__ Bv, float* __restrict__ sum)
{
    const int b = blockIdx.x / C;
    const int c = blockIdx.x % C;
    const int d = threadIdx.x;

    float wk[KK], bk[KK];
    #pragma unroll
    for (int k = 0; k < KK; ++k) { wk[k] = W[k * DD + d]; bk[k] = Bv[k * DD + d]; }

    float cv[KK];
    float A[KK][KK];
    #pragma unroll
    for (int k = 0; k < KK; ++k) {
        cv[k] = -INFINITY;
        #pragma unroll
        for (int j = 0; j < KK; ++j) A[k][j] = -INFINITY;
    }

    const float* xp = X + (b * TT + c * L) * DD + d;
    float x0[U], x1[U];
    #pragma unroll
    for (int u = 0; u < U; ++u) x0[u] = xp[u * DD];

    // dynamic loop: 16-step body fits I$; prefetch distance = 8 steps
    #pragma unroll 1
    for (int ib = 0; ib + 2 < NB; ib += 2) {
        #pragma unroll
        for (int u = 0; u < U; ++u) x1[u] = xp[(U + u) * DD];
        #pragma unroll
        for (int u = 0; u < U; ++u) step_sum(x0[u], wk, bk, A, cv);
        #pragma unroll
        for (int u = 0; u < U; ++u) x0[u] = xp[(2 * U + u) * DD];
        #pragma unroll
        for (int u = 0; u < U; ++u) step_sum(x1[u], wk, bk, A, cv);
        xp += 2 * U * DD;
    }
    // tail: batches NB-2 (in x0) and NB-1
    #pragma unroll
    for (int u = 0; u < U; ++u) x1[u] = xp[(U + u) * DD];
    #pragma unroll
    for (int u = 0; u < U; ++u) step_sum(x0[u], wk, bk, A, cv);
    #pragma unroll
    for (int u = 0; u < U; ++u) step_sum(x1[u], wk, bk, A, cv);

    // plane-layout store: 36 coalesced 256B stores
    float* sp = sum + blockIdx.x * NSUM * DD + d;   // region = b*C + c
    #pragma unroll
    for (int k = 0; k < KK; ++k) sp[k * DD] = cv[k];
    #pragma unroll
    for (int k = 1; k < KK; ++k) {
        #pragma unroll
        for (int j = 0; j < k; ++j) sp[tri(k, j) * DD] = A[k][j];
    }
}

// plane-layout map load: 36 coalesced scalar loads into registers
__device__ __forceinline__ void ld_map(const float* __restrict__ p,
                                       float (&m)[NSUM])
{
    #pragma unroll
    for (int i = 0; i < NSUM; ++i) m[i] = p[i * DD];
}

// s <- apply(map m, s)
__device__ __forceinline__ void apply_map(const float (&m)[NSUM], float (&s)[KK])
{
    float ns[KK];
    #pragma unroll
    for (int k = 0; k < KK; ++k) ns[k] = fmaxf(m[k], s[k]);   // c[k], diag
    #pragma unroll
    for (int k = 1; k < KK; ++k) {
        #pragma unroll
        for (int j = 0; j < k; ++j) ns[k] = fmaxf(ns[k], m[tri(k, j)] + s[j]);
    }
    #pragma unroll
    for (int k = 0; k < KK; ++k) s[k] = ns[k];
}

// (R,cv) <- compose(map m, (R,cv))   [m applied AFTER accumulated (R,cv)]
__device__ __forceinline__ void compose_map(const float (&m)[NSUM],
                                            float (&R)[KK][KK], float (&cv)[KK])
{
    float nc[KK];
    #pragma unroll
    for (int i = 0; i < KK; ++i) {
        float v = fmaxf(m[i], cv[i]);
        #pragma unroll
        for (int j = 0; j < i; ++j) v = fmaxf(v, m[tri(i, j)] + cv[j]);
        nc[i] = v;
    }
    float nR[KK][KK];
    #pragma unroll
    for (int i = 1; i < KK; ++i) {
        #pragma unroll
        for (int j = 0; j < i; ++j) {
            float v = fmaxf(R[i][j], m[tri(i, j)]);
            #pragma unroll
            for (int mm = j + 1; mm < i; ++mm)
                v = fmaxf(v, m[tri(i, mm)] + R[mm][j]);
            nR[i][j] = v;
        }
    }
    #pragma unroll
    for (int i = 0; i < KK; ++i) {
        cv[i] = nc[i];
        #pragma unroll
        for (int j = 0; j < i; ++j) R[i][j] = nR[i][j];
    }
}

// ---- pass 2a: one block per (b, group); compose G chunk maps ----
__global__ __launch_bounds__(256) void pass2a_groups(
    const float* __restrict__ sum, float* __restrict__ gsum)
{
    const int b = blockIdx.x / NG;
    const int g = blockIdx.x % NG;
    const int d = threadIdx.x;

    float R[KK][KK], cv[KK];
    #pragma unroll
    for (int i = 0; i < KK; ++i) {
        cv[i] = -INFINITY;
        #pragma unroll
        for (int j = 0; j < KK; ++j) R[i][j] = -INFINITY;
    }

    const float* mp = sum + (b * C + g * G) * NSUM * DD + d;
    float m0[NSUM], m1[NSUM];
    ld_map(mp, m0);
    #pragma unroll 1
    for (int ci = 0; ci + 2 < G; ci += 2) {
        ld_map(mp + NSUM * DD, m1);
        compose_map(m0, R, cv);
        ld_map(mp + 2 * NSUM * DD, m0);
        compose_map(m1, R, cv);
        mp += 2 * NSUM * DD;
    }
    ld_map(mp + NSUM * DD, m1);
    compose_map(m0, R, cv);
    compose_map(m1, R, cv);

    float* gp = gsum + blockIdx.x * NSUM * DD + d;  // region = b*NG + g
    #pragma unroll
    for (int i = 0; i < KK; ++i) gp[i * DD] = cv[i];
    #pragma unroll
    for (int i = 1; i < KK; ++i) {
        #pragma unroll
        for (int j = 0; j < i; ++j) gp[tri(i, j) * DD] = R[i][j];
    }
}

// ---- pass 2b: one block per b; serial apply over NG group maps ----
__global__ __launch_bounds__(256) void pass2b_scan_groups(
    const float* __restrict__ gsum, float* __restrict__ ginfl)
{
    const int b = blockIdx.x;
    const int d = threadIdx.x;

    float s[KK];
    #pragma unroll
    for (int k = 0; k < KK; ++k) s[k] = -INFINITY;

    const float* mp = gsum + b * NG * NSUM * DD + d;
    float* ip = ginfl + b * NG * KK * DD + d;
    float m0[NSUM], m1[NSUM];
    ld_map(mp, m0);
    #pragma unroll 1
    for (int g = 0; g + 2 < NG; g += 2) {
        ld_map(mp + NSUM * DD, m1);
        #pragma unroll
        for (int k = 0; k < KK; ++k) ip[k * DD] = s[k];      // inflow BEFORE g
        apply_map(m0, s);
        ld_map(mp + 2 * NSUM * DD, m0);
        #pragma unroll
        for (int k = 0; k < KK; ++k) ip[KK * DD + k * DD] = s[k];
        apply_map(m1, s);
        mp += 2 * NSUM * DD;
        ip += 2 * KK * DD;
    }
    ld_map(mp + NSUM * DD, m1);
    #pragma unroll
    for (int k = 0; k < KK; ++k) ip[k * DD] = s[k];
    apply_map(m0, s);
    #pragma unroll
    for (int k = 0; k < KK; ++k) ip[KK * DD + k * DD] = s[k];
    apply_map(m1, s);
}

// ---- pass 2c: one block per (b, group); replay chunk maps -> chunk inflows ----
__global__ __launch_bounds__(256) void pass2c_chunk_inflows(
    const float* __restrict__ sum, const float* __restrict__ ginfl,
    float* __restrict__ infl)
{
    const int b = blockIdx.x / NG;
    const int g = blockIdx.x % NG;
    const int d = threadIdx.x;

    float s[KK];
    {
        const float* gp = ginfl + blockIdx.x * KK * DD + d;  // region = b*NG+g
        #pragma unroll
        for (int k = 0; k < KK; ++k) s[k] = gp[k * DD];
    }

    const float* mp = sum + (b * C + g * G) * NSUM * DD + d;
    float* ip = infl + (b * C + g * G) * KK * DD + d;
    float m0[NSUM], m1[NSUM];
    ld_map(mp, m0);
    #pragma unroll 1
    for (int ci = 0; ci + 2 < G; ci += 2) {
        ld_map(mp + NSUM * DD, m1);
        #pragma unroll
        for (int k = 0; k < KK; ++k) ip[k * DD] = s[k];      // inflow BEFORE c
        apply_map(m0, s);
        ld_map(mp + 2 * NSUM * DD, m0);
        #pragma unroll
        for (int k = 0; k < KK; ++k) ip[KK * DD + k * DD] = s[k];
        apply_map(m1, s);
        mp += 2 * NSUM * DD;
        ip += 2 * KK * DD;
    }
    ld_map(mp + NSUM * DD, m1);
    #pragma unroll
    for (int k = 0; k < KK; ++k) ip[k * DD] = s[k];
    apply_map(m0, s);
    #pragma unroll
    for (int k = 0; k < KK; ++k) ip[KK * DD + k * DD] = s[k];
    apply_map(m1, s);
}

// ---- pass 3: one block per (b, chunk); scan from inflow, emit outputs ----
__device__ __forceinline__ void step_scan(float x, const float (&wk)[KK],
                                          const float (&bk)[KK], float (&s)[KK])
{
    float g[KK];
    #pragma unroll
    for (int k = 0; k < KK; ++k) g[k] = fmaf(x, wk[k], bk[k]);
    #pragma unroll
    for (int k = KK - 1; k >= 1; --k) s[k] = fmaxf(s[k], s[k - 1] + g[k]);
    s[0] = fmaxf(s[0], g[0]);
}

__global__ __launch_bounds__(256) void pass3_scan(
    const float* __restrict__ X, const float* __restrict__ W,
    const float* __restrict__ Bv, const float* __restrict__ infl,
    float* __restrict__ out)
{
    const int b = blockIdx.x / C;
    const int c = blockIdx.x % C;
    const int d = threadIdx.x;

    float wk[KK], bk[KK];
    #pragma unroll
    for (int k = 0; k < KK; ++k) { wk[k] = W[k * DD + d]; bk[k] = Bv[k * DD + d]; }

    float s[KK];
    {
        const float* ip = infl + blockIdx.x * KK * DD + d;   // region = b*C+c
        #pragma unroll
        for (int k = 0; k < KK; ++k) s[k] = ip[k * DD];
    }

    const int t0 = c * L;
    const float* xp = X + (b * TT + t0) * DD + d;
    // FIXED base: indexed by cumulative in-chunk step t only (op never advances)
    float* op = out + b * TOUT * DD + (t0 - (KK - 1)) * DD + d;

    float x0[U], x1[U];
    #pragma unroll
    for (int u = 0; u < U; ++u) x0[u] = xp[u * DD];

    int t = 0;                                   // step within chunk
    #pragma unroll 1
    for (int ib = 0; ib + 2 < NB; ib += 2) {
        #pragma unroll
        for (int u = 0; u < U; ++u) x1[u] = xp[(U + u) * DD];
        #pragma unroll
        for (int u = 0; u < U; ++u) {
            step_scan(x0[u], wk, bk, s);
            if (t0 + t >= KK - 1) op[t * DD] = s[KK - 1];
            ++t;
        }
        #pragma unroll
        for (int u = 0; u < U; ++u) x0[u] = xp[(2 * U + u) * DD];
        #pragma unroll
        for (int u = 0; u < U; ++u) {
            step_scan(x1[u], wk, bk, s);
            if (t0 + t >= KK - 1) op[t * DD] = s[KK - 1];
            ++t;
        }
        xp += 2 * U * DD;
    }
    #pragma unroll
    for (int u = 0; u < U; ++u) x1[u] = xp[(U + u) * DD];
    #pragma unroll
    for (int u = 0; u < U; ++u) {
        step_scan(x0[u], wk, bk, s);
        if (t0 + t >= KK - 1) op[t * DD] = s[KK - 1];
        ++t;
    }
    #pragma unroll
    for (int u = 0; u < U; ++u) {
        step_scan(x1[u], wk, bk, s);
        if (t0 + t >= KK - 1) op[t * DD] = s[KK - 1];
        ++t;
    }
}
} // namespace

extern "C" void kernel_launch(void* const* d_in, const int* in_sizes, int n_in,
                              void* d_out, int out_size, void* d_ws, size_t ws_size,
                              hipStream_t stream)
{
    const float* X  = (const float*)d_in[0];
    const float* W  = (const float*)d_in[1];
    const float* Bv = (const float*)d_in[2];
    float* out = (float*)d_out;

    // ws: sum 37.7 MB + gsum 4.7 MB + ginfl 1.05 MB + infl 8.4 MB = 51.9 MB
    float* sum   = (float*)d_ws;
    float* gsum  = sum   + (size_t)BB * C  * NSUM * DD;
    float* ginfl = gsum  + (size_t)BB * NG * NSUM * DD;
    float* infl  = ginfl + (size_t)BB * NG * KK   * DD;

    pass1_summaries<<<BB * C, 256, 0, stream>>>(X, W, Bv, sum);
    pass2a_groups<<<BB * NG, 256, 0, stream>>>(sum, gsum);
    pass2b_scan_groups<<<BB, 256, 0, stream>>>(gsum, ginfl);
    pass2c_chunk_inflows<<<BB * NG, 256, 0, stream>>>(sum, ginfl, infl);
    pass3_scan<<<BB * C, 256, 0, stream>>>(X, W, Bv, infl, out);
}